// Round 8
// baseline (245.995 us; speedup 1.0000x reference)
//
#include <hip/hip_runtime.h>

// out[b,n] = prod_d psi((x[b,d]-c[n,d])/s[n,d]),  psi(z)=(1-z^2)exp(-z^2/2)
// Per 16-d group: prod psi = [prod(1-z^2)] * exp2(-0.72135*sum z^2), z via
// z = fma(x, r, -cr), {cr,r} = {c/s, 1/s}. Group bound: |1-z^2|<=~1e2 ->
// p <= 1e32 < 3.4e38; each group factor <= 1 -> acc in [0,1]. fp32-only.
//
// R16: single fused kernel, NO workspace. Ledger recalibration across
// R8..R15: dur_us ~= wavelet + ~55us fixed, of which 41.5us is the 256 MiB
// d_ws poison fill the harness runs because we used d_ws for a 256 KB
// table. Fold prep into the block's param staging (r=1/s, cr=c*r computed
// during the LDS write; identical numerics to the prep kernel) and drop
// d_ws -> if the poison is ws-conditional, -41.5us; else still -prep.
// R15 post-mortem (wavelet 44.6us, VALUBusy 60%, memory clean): residual
// stall = 3-blocks/CU capacity vs 4-blocks grid -> straggler round at
// 1 block/CU (44.6 = 33.5 + 11 starved). Fix: LDS = 32 KB param slab only
// (x-transpose aliased on top, output stage dropped -> per-lane 4B stores;
// consecutive ni hit the same 64B line 16x, L2 merges -- R14/15 WRITE_SIZE
// proved merging works) -> 4 resident blocks/CU, single round.
// Inner loop (the part of R15 that worked): zero VMEM/SMEM, uniform
// ds_read_b128 broadcasts + register-resident x; unroll 1 on ni and k
// caps liveness. VGPR ~108 < 128 cap (launch_bounds(256,2)).

#define DD 64

typedef float v4f __attribute__((ext_vector_type(4)));

__global__ __launch_bounds__(256, 2)
void wavelet_fused(const float* __restrict__ x,
                   const float* __restrict__ c,
                   const float* __restrict__ s,
                   float* __restrict__ out, int B, int N) {
    // pool: par[64n][32 qw] = 32 KB ; phase-1 xs[64][65] f32 aliased on top
    __shared__ __align__(16) char pool[32 * 1024];
    float* xs = (float*)pool;      // [64][65], 16.64 KB, dies at 2nd barrier
    v4f* par = (v4f*)pool;         // [64 n][32 qwords of {cr,r,cr,r}]

    int t = threadIdx.x;
    int lane = t & 63;
    int wv = __builtin_amdgcn_readfirstlane(t >> 6);   // wave-uniform
    int bblk = blockIdx.x * 64;                        // block's 64 b rows
    int nblk = blockIdx.y * 64;                        // block's 64 n cols

    // phase 1: stage x[bblk..+63][0..63] coalesced, padded rows (65)
    {
        const float4* xg = (const float4*)(x + (size_t)bblk * DD);
#pragma unroll
        for (int j = 0; j < 4; ++j) {
            int idx = j * 256 + t;
            int row = idx >> 4, c4 = idx & 15;
            float4 v = xg[idx];
            float* p = &xs[row * 65 + c4 * 4];
            p[0] = v.x; p[1] = v.y; p[2] = v.z; p[3] = v.w;
        }
    }
    __syncthreads();

    // transpose into registers: lane = b owns x[b][0..63] (64 VGPRs).
    // bank = (65*lane+d)%32 = (lane+d)%32 -> 2 lanes/bank = free (m136).
    float xr[DD];
#pragma unroll
    for (int d = 0; d < DD; ++d) xr[d] = xs[lane * 65 + d];
    __syncthreads();   // xs dead -> par may overwrite the region

    // phase 2 (prep folded in): stage param slab for n = nblk..+63.
    // coalesced float2 reads of c,s; r = 1/s (exact div, matches the old
    // prep kernel bit-for-bit); ds_write_b128 at 16B stride, conflict-free.
    {
        const float2* cg = (const float2*)(c + (size_t)nblk * DD);
        const float2* sg = (const float2*)(s + (size_t)nblk * DD);
#pragma unroll
        for (int j = 0; j < 8; ++j) {
            int i = j * 256 + t;          // par qword index; dims 2i, 2i+1
            float2 cc = cg[i];
            float2 ss = sg[i];
            float r0 = 1.0f / ss.x;
            float r1 = 1.0f / ss.y;
            par[i] = (v4f){cc.x * r0, r0, cc.y * r1, r1};
        }
    }
    __syncthreads();

    // phase 3: n loop. wave wv owns n = nblk + wv*16 + ni. Inner loop has
    // zero VMEM/SMEM -- only uniform-address ds_read_b128 broadcasts.
    float* orow = out + (size_t)(bblk + lane) * N + nblk + wv * 16;
#pragma unroll 1
    for (int ni = 0; ni < 16; ++ni) {
        const v4f* Pn = par + (wv * 16 + ni) * 32;
        float acc = 1.0f;
#pragma unroll 1
        for (int k = 0; k < 4; ++k) {        // 4 chunks of 16 d
            float p = 1.0f, s2 = 0.0f;
#pragma unroll
            for (int i = 0; i < 8; ++i) {    // 2 d per qword
                v4f q = Pn[k * 8 + i];       // {cr0, r0, cr1, r1} bcast
                float z0 = __builtin_fmaf(xr[k * 16 + 2 * i], q.y, -q.x);
                float z1 = __builtin_fmaf(xr[k * 16 + 2 * i + 1], q.w, -q.z);
                float w0 = z0 * z0;
                float w1 = z1 * z1;
                p = __builtin_fmaf(-w0, p, p);   // p *= (1-w0)
                p = __builtin_fmaf(-w1, p, p);
                s2 += w0;
                s2 += w1;
            }
            acc *= p * __builtin_exp2f(-0.72134752f * s2);
        }
        // per-lane 4B store; ni=0..15 fill one 64B line per b row -> L2
        // write-merges (R14/15: WRITE_SIZE stayed at the 16.4 MB logical).
        orow[ni] = acc;
    }
}

extern "C" void kernel_launch(void* const* d_in, const int* in_sizes, int n_in,
                              void* d_out, int out_size, void* d_ws, size_t ws_size,
                              hipStream_t stream) {
    const float* x = (const float*)d_in[0];
    const float* c = (const float*)d_in[1];
    const float* s = (const float*)d_in[2];
    float* out = (float*)d_out;

    int B = in_sizes[0] / DD;    // 8192
    int N = in_sizes[1] / DD;    // 512

    (void)d_ws; (void)ws_size;   // workspace intentionally unused (R16)

    // grid: x = b strips of 64 (lane=b), y = n groups of 64 (4 waves x 16)
    dim3 grid(B / 64, N / 64);   // 128 x 8 = 1024 blocks = 4/CU, one round
    wavelet_fused<<<grid, 256, 0, stream>>>(x, c, s, out, B, N);
}